// Round 7
// baseline (527.748 us; speedup 1.0000x reference)
//
#include <hip/hip_runtime.h>
#include <hip/hip_bf16.h>
#include <stdint.h>

#define B_ 4
#define S_ 4096
#define D_ 2048
#define M_ 512
#define E_ (D_ + M_)   // 2560 combined width
#define BS_ (B_ * S_)  // 16384 rows
#define CH_ 32         // scan chunks per sequence
#define CL_ 128        // chunk length (CH_*CL_ == S_)

typedef __attribute__((ext_vector_type(8))) short short8;
typedef __attribute__((ext_vector_type(4))) short short4e;
typedef __attribute__((ext_vector_type(4))) float float4e;

__device__ __forceinline__ unsigned short f2bf(float f) {
    unsigned int u = __float_as_uint(f);
    u = (u + 0x7fffu + ((u >> 16) & 1u)) >> 16;   // RNE
    return (unsigned short)u;
}
__device__ __forceinline__ float bf2f(unsigned short h) {
    return __uint_as_float(((unsigned int)h) << 16);
}
__device__ __forceinline__ float sigmoidf(float x) {
    return 1.0f / (1.0f + expf(-x));
}

// ---- async global -> LDS, 16B per lane -------------------------------------
__device__ __forceinline__ void load_lds16(const unsigned short* g, unsigned short* l) {
    __builtin_amdgcn_global_load_lds(
        (const __attribute__((address_space(1))) unsigned int*)g,
        (__attribute__((address_space(3))) unsigned int*)l,
        16, 0, 0);
}

// ---- fp32 -> bf16 conversion: x into comb[:, 0:2048] (row stride E_) -------
__global__ void conv_x_kernel(const float* __restrict__ x, unsigned short* __restrict__ comb) {
    int i = blockIdx.x * blockDim.x + threadIdx.x;
    const int n4 = BS_ * D_ / 4;
    const int stride = gridDim.x * blockDim.x;
    for (; i < n4; i += stride) {
        int flat = i << 2;
        int row = flat >> 11;              // D_ = 2048
        int col = flat & (D_ - 1);
        float4 xv = ((const float4*)x)[i];
        short4e o = { (short)f2bf(xv.x), (short)f2bf(xv.y),
                      (short)f2bf(xv.z), (short)f2bf(xv.w) };
        *(short4e*)(comb + (size_t)row * E_ + col) = o;
    }
}

// ---- fp32 -> bf16 for both weight matrices in one launch -------------------
__global__ void conv_w_kernel(const float* __restrict__ Wv, unsigned short* __restrict__ Wvb,
                              const float* __restrict__ Wg, unsigned short* __restrict__ Wgb) {
    const int nv4 = M_ * D_ / 4;
    const int ng4 = D_ * E_ / 4;
    int i = blockIdx.x * blockDim.x + threadIdx.x;
    const int stride = gridDim.x * blockDim.x;
    for (; i < nv4 + ng4; i += stride) {
        const float* in;
        unsigned short* out;
        int j;
        if (i < nv4) { in = Wv; out = Wvb; j = i; }
        else         { in = Wg; out = Wgb; j = i - nv4; }
        float4 xv = ((const float4*)in)[j];
        short4e o = { (short)f2bf(xv.x), (short)f2bf(xv.y),
                      (short)f2bf(xv.z), (short)f2bf(xv.w) };
        ((short4e*)out)[j] = o;
    }
}

// ---- bf16 GEMM, B^T layout: C[m,n] = sum_k A[m,k]*B[n,k] (+bias, +resid) ---
// 2-barrier K-loop structure, kept for GEMM1 (N=512 -> needs small-N tiling)
template<int BM, int BN, bool ADDX, bool OUT_BF16>
__global__ __launch_bounds__(256) void gemm_bt(
    const unsigned short* __restrict__ A, int lda,
    const unsigned short* __restrict__ Bm, int ldb,
    void* __restrict__ Cv, int ldc,
    const float* __restrict__ bias,
    const unsigned short* __restrict__ resid, int resid_ld,
    int K)
{
    constexpr int MI = BM / 32;
    constexpr int NJ = BN / 32;
    constexpr int NGA = BM / 32;
    constexpr int NGB = BN / 32;

    __shared__ unsigned short As[BM * 64];
    __shared__ unsigned short Bs[BN * 64];

    const int tid  = threadIdx.x;
    const int lane = tid & 63;
    const int wave = __builtin_amdgcn_readfirstlane(tid >> 6);
    const int bm0  = blockIdx.x * BM;
    const int bn0  = blockIdx.y * BN;
    const int wm   = wave & 1;
    const int wn   = wave >> 1;
    const int lm   = lane & 15;
    const int quad = lane >> 4;

    const unsigned short* ag[NGA];
    unsigned short* al[NGA];
#pragma unroll
    for (int i = 0; i < NGA; ++i) {
        int g = i * 256 + tid;
        int r = g >> 3, c = g & 7;
        int cg = c ^ (r & 7);
        ag[i] = A + (size_t)(bm0 + r) * lda + cg * 8;
        al[i] = As + (i * 256 + wave * 64) * 8;
    }
    const unsigned short* bgp[NGB];
    unsigned short* bl[NGB];
#pragma unroll
    for (int i = 0; i < NGB; ++i) {
        int g = i * 256 + tid;
        int r = g >> 3, c = g & 7;
        int cg = c ^ (r & 7);
        bgp[i] = Bm + (size_t)(bn0 + r) * ldb + cg * 8;
        bl[i] = Bs + (i * 256 + wave * 64) * 8;
    }

    float4e acc[MI][NJ];
    const float4e zero = {0.f, 0.f, 0.f, 0.f};
#pragma unroll
    for (int i = 0; i < MI; ++i)
#pragma unroll
        for (int j = 0; j < NJ; ++j) acc[i][j] = zero;

    for (int k0 = 0; k0 < K; k0 += 64) {
#pragma unroll
        for (int i = 0; i < NGA; ++i) load_lds16(ag[i] + k0, al[i]);
#pragma unroll
        for (int i = 0; i < NGB; ++i) load_lds16(bgp[i] + k0, bl[i]);
        __syncthreads();
#pragma unroll
        for (int kk = 0; kk < 2; ++kk) {
            short8 af[MI], bf[NJ];
#pragma unroll
            for (int i = 0; i < MI; ++i) {
                int ra = wm * (BM / 2) + i * 16 + lm;
                af[i] = *(const short8*)(As + ra * 64 + (((kk * 4 + quad) ^ (ra & 7)) * 8));
            }
#pragma unroll
            for (int j = 0; j < NJ; ++j) {
                int rb = wn * (BN / 2) + j * 16 + lm;
                bf[j] = *(const short8*)(Bs + rb * 64 + (((kk * 4 + quad) ^ (rb & 7)) * 8));
            }
#pragma unroll
            for (int i = 0; i < MI; ++i)
#pragma unroll
                for (int j = 0; j < NJ; ++j)
                    acc[i][j] = __builtin_amdgcn_mfma_f32_16x16x32_bf16(af[i], bf[j], acc[i][j], 0, 0, 0);
        }
        __syncthreads();
    }

#pragma unroll
    for (int i = 0; i < MI; ++i) {
#pragma unroll
        for (int j = 0; j < NJ; ++j) {
            int row = bm0 + wm * (BM / 2) + i * 16 + quad * 4;
            int col = bn0 + wn * (BN / 2) + j * 16 + lm;
            float bb = bias[col];
#pragma unroll
            for (int r = 0; r < 4; ++r) {
                size_t idx = (size_t)(row + r) * ldc + col;
                float val = acc[i][j][r] + bb;
                if (ADDX) val += bf2f(resid[(size_t)(row + r) * resid_ld + col]);
                if (OUT_BF16) ((unsigned short*)Cv)[idx] = f2bf(val);
                else          ((float*)Cv)[idx] = val;
            }
        }
    }
}

// ---- 256x256 GEMM: BK=32, 4-buffer LDS ring, 8 waves, ONE barrier/tile -----
// r6 post-mortem (r5: 219us, MfmaUtil 33, VALU 12.5, conflicts 0, FETCH fixed):
// per-tile 3288 cyc vs 1242 MFMA floor == the serial model {drain 64 reads}
// then {MFMA} per phase + 4 barriers. The mid-tile barriers were UNNECESSARY
// with a 4-deep ring (reads hit buf[t], stages hit buf[t+3] — disjoint), and
// the explicit lgkmcnt(0)+sched_barrier before MFMA destroyed the compiler's
// progressive per-use lgkmcnt interleave (m97-verified behavior).
// r6: one barrier per K-tile. Per tile: issue 4 stages (t+3) -> 12 plain
// ds_reads (bf first for a progressive wait ladder) -> 32 MFMA (compiler
// inserts fine lgkm waits) -> vmcnt(8) (counted, never 0) -> s_barrier.
// Boundary hazards: each wave's reads of buf[t] are lgkm-retired before its
// MFMAs issue, which precede the barrier in order -> all reads done before
// anyone stages into buf[t] at t+1. vmcnt(8) retires tile t+1's 4 loads
// (12 outstanding: t+1,t+2,t+3) before they're read next tile.
template<bool ADDX, bool OUT_BF16, int MT>
__global__ __launch_bounds__(512, 2) void gemm_bt8(
    const unsigned short* __restrict__ A, int lda,
    const unsigned short* __restrict__ Bm, int ldb,
    void* __restrict__ Cv, int ldc,
    const float* __restrict__ bias,
    const unsigned short* __restrict__ resid, int resid_ld,
    int K)
{
    __shared__ unsigned short As[4][256 * 32];   // 64 KB
    __shared__ unsigned short Bs[4][256 * 32];   // 64 KB

    const int tid  = threadIdx.x;
    const int lane = tid & 63;
    const int wave = __builtin_amdgcn_readfirstlane(tid >> 6);
    const int wm   = wave >> 2;      // 0..1  (M half)
    const int wn   = wave & 3;       // 0..3  (N quarter)
    const int lm   = lane & 15;
    const int quad = lane >> 4;

    // XCD mapping: xcd = bid&7 owns row-tiles [xcd*RPX, (xcd+1)*RPX),
    // sweeping columns slowly. A partitioned disjointly, B broadcast via L3.
    constexpr int RPX = MT / 8;
    const int bid = blockIdx.x;
    const int xcd = bid & 7;
    const int w   = bid >> 3;
    const int row = xcd * RPX + (w % RPX);
    const int col = w / RPX;
    const int bm0 = row * 256;
    const int bn0 = col * 256;

    // staging: LDS granule (r,c) holds global granule (r, c^((r>>1)&3)), 16B
    const unsigned short* agp[2];
    const unsigned short* bgp[2];
    int soffl[2];
#pragma unroll
    for (int s = 0; s < 2; ++s) {
        int g = s * 512 + tid;
        int r = g >> 2, c = g & 3;
        int cg = c ^ ((r >> 1) & 3);
        agp[s] = A  + (size_t)(bm0 + r) * lda + cg * 8;
        bgp[s] = Bm + (size_t)(bn0 + r) * ldb + cg * 8;
        soffl[s] = s * 4096 + wave * 512;        // wave-uniform lds base (shorts)
    }

    float4e acc[8][4];
    const float4e zero = {0.f, 0.f, 0.f, 0.f};
#pragma unroll
    for (int i = 0; i < 8; ++i)
#pragma unroll
        for (int j = 0; j < 4; ++j) acc[i][j] = zero;

    const int NT = K >> 5;           // K-tiles of 32

    // prologue: stage tiles 0,1,2 (12 loads); wait oldest 4 (tile 0)
#pragma unroll
    for (int s = 0; s < 2; ++s) load_lds16(agp[s], &As[0][soffl[s]]);
#pragma unroll
    for (int s = 0; s < 2; ++s) load_lds16(bgp[s], &Bs[0][soffl[s]]);
#pragma unroll
    for (int s = 0; s < 2; ++s) load_lds16(agp[s] + 32, &As[1][soffl[s]]);
#pragma unroll
    for (int s = 0; s < 2; ++s) load_lds16(bgp[s] + 32, &Bs[1][soffl[s]]);
#pragma unroll
    for (int s = 0; s < 2; ++s) load_lds16(agp[s] + 64, &As[2][soffl[s]]);
#pragma unroll
    for (int s = 0; s < 2; ++s) load_lds16(bgp[s] + 64, &Bs[2][soffl[s]]);
    asm volatile("s_waitcnt vmcnt(8)");
    __builtin_amdgcn_sched_barrier(0);
    __builtin_amdgcn_s_barrier();
    __builtin_amdgcn_sched_barrier(0);

    // per-lane ds_read offsets (shorts); granule = quad ^ ((row>>1)&3), and
    // (row>>1)&3 == (lm>>1)&3 since all sub-tile bases are multiples of 16
    const int aoff = (wm * 128 + lm) * 32 + ((quad ^ ((lm >> 1) & 3)) << 3);
    const int boff = (wn * 64  + lm) * 32 + ((quad ^ ((lm >> 1) & 3)) << 3);

    for (int t = 0; t < NT; ++t) {
        const int buf = t & 3;
        const unsigned short* Ab = As[buf];
        const unsigned short* Bb = Bs[buf];
        int tp = t + 3; if (tp > NT - 1) tp = NT - 1;   // clamp: dummy re-stage
        const int kpre = tp << 5;
        const int pbuf = (t + 3) & 3;

        // issue prefetch stages for tile t+3 first (deep latency cover)
#pragma unroll
        for (int s = 0; s < 2; ++s) load_lds16(agp[s] + kpre, &As[pbuf][soffl[s]]);
#pragma unroll
        for (int s = 0; s < 2; ++s) load_lds16(bgp[s] + kpre, &Bs[pbuf][soffl[s]]);

        // 12 fragment reads, plain loads: compiler emits progressive lgkmcnt
        // per MFMA use. bf first so the first MFMAs' operands arrive earliest.
        short8 bf[4], af[8];
#pragma unroll
        for (int j = 0; j < 4; ++j) bf[j] = *(const short8*)(Bb + boff + j * 512);
#pragma unroll
        for (int i = 0; i < 8; ++i) af[i] = *(const short8*)(Ab + aoff + i * 512);

        __builtin_amdgcn_s_setprio(1);
#pragma unroll
        for (int i = 0; i < 8; ++i)
#pragma unroll
            for (int j = 0; j < 4; ++j)
                acc[i][j] = __builtin_amdgcn_mfma_f32_16x16x32_bf16(af[i], bf[j], acc[i][j], 0, 0, 0);
        __builtin_amdgcn_s_setprio(0);

        asm volatile("s_waitcnt vmcnt(8)");   // tile t+1 landed (counted, never 0)
        __builtin_amdgcn_sched_barrier(0);
        __builtin_amdgcn_s_barrier();
        __builtin_amdgcn_sched_barrier(0);
    }

    // epilogue: C/D layout col = lane&15, row = quad*4 + reg
#pragma unroll
    for (int i = 0; i < 8; ++i) {
#pragma unroll
        for (int j = 0; j < 4; ++j) {
            int crow = bm0 + wm * 128 + i * 16 + quad * 4;
            int ccol = bn0 + wn * 64  + j * 16 + lm;
            float bb = bias[ccol];
#pragma unroll
            for (int r = 0; r < 4; ++r) {
                size_t idx = (size_t)(crow + r) * ldc + ccol;
                float val = acc[i][j][r] + bb;
                if (ADDX) val += bf2f(resid[(size_t)(crow + r) * resid_ld + ccol]);
                if (OUT_BF16) ((unsigned short*)Cv)[idx] = f2bf(val);
                else          ((float*)Cv)[idx] = val;
            }
        }
    }
}

// ---- scan pass 1: per-chunk local end state (init 0), bf16 v ---------------
__global__ void scan_p1(const unsigned short* __restrict__ v, const float* __restrict__ tdp,
                        float* __restrict__ Ebuf) {
    int tid = blockIdx.x * blockDim.x + threadIdx.x;
    int m = tid & (M_ - 1);
    int c = (tid >> 9) & (CH_ - 1);
    int b = tid >> 14;
    float td = 0.9f * sigmoidf(tdp[m]) + 0.1f;
    const unsigned short* vp = v + (size_t)(b * S_ + c * CL_) * M_ + m;
    float s = 0.f;
#pragma unroll 4
    for (int t = 0; t < CL_; ++t) s = td * s + bf2f(vp[(size_t)t * M_]);
    Ebuf[(b * CH_ + c) * M_ + m] = s;
}

// ---- scan pass 2 (prefix inlined) + emit wv bf16 + final state -------------
__global__ void scan_p3(const unsigned short* __restrict__ v, const float* __restrict__ tdp,
                        const float* __restrict__ tfp, const float* __restrict__ ms,
                        const float* __restrict__ Ebuf, unsigned short* __restrict__ comb,
                        float* __restrict__ out_state) {
    int tid = blockIdx.x * blockDim.x + threadIdx.x;
    int m = tid & (M_ - 1);
    int c = (tid >> 9) & (CH_ - 1);
    int b = tid >> 14;
    float td  = 0.9f * sigmoidf(tdp[m]) + 0.1f;
    float a = td;
#pragma unroll
    for (int i = 0; i < 7; ++i) a *= a;                // td^128
    float s = 0.f;
    for (int cp = 0; cp < c; ++cp)
        s = a * s + Ebuf[(b * CH_ + cp) * M_ + m];
    float add = ms[b * M_ + m] * sigmoidf(tfp[m]);
    const unsigned short* vp = v + (size_t)(b * S_ + c * CL_) * M_ + m;
    unsigned short* cp_ = comb + (size_t)(b * S_ + c * CL_) * E_ + D_ + m;
    float w = 0.f;
#pragma unroll 4
    for (int t = 0; t < CL_; ++t) {
        s = td * s + bf2f(vp[(size_t)t * M_]);
        w = s + add;
        cp_[(size_t)t * E_] = f2bf(w);
    }
    if (c == CH_ - 1) out_state[b * M_ + m] = w;
}

extern "C" void kernel_launch(void* const* d_in, const int* in_sizes, int n_in,
                              void* d_out, int out_size, void* d_ws, size_t ws_size,
                              hipStream_t stream) {
    const float* x    = (const float*)d_in[0];
    const float* ms   = (const float*)d_in[1];
    // d_in[2]=Wk, d_in[3]=bk are dead code in the reference
    const float* Wv   = (const float*)d_in[4];
    const float* bv   = (const float*)d_in[5];
    const float* Wg   = (const float*)d_in[6];
    const float* bg   = (const float*)d_in[7];
    const float* tdec = (const float*)d_in[8];
    const float* tfir = (const float*)d_in[9];

    float* out       = (float*)d_out;
    float* out_state = out + (size_t)BS_ * D_;

    char* ws = (char*)d_ws;
    size_t off = 0;
    unsigned short* comb = (unsigned short*)(ws + off); off += (size_t)BS_ * E_ * 2;  // 84 MB
    unsigned short* vbuf = (unsigned short*)(ws + off); off += (size_t)BS_ * M_ * 2;  // 16.8 MB
    unsigned short* Wvb  = (unsigned short*)(ws + off); off += (size_t)M_ * D_ * 2;   // 2 MB
    unsigned short* Wgb  = (unsigned short*)(ws + off); off += (size_t)D_ * E_ * 2;   // 10.5 MB
    float*          Ebuf = (float*)(ws + off);          off += (size_t)B_ * CH_ * M_ * 4;

    // 1. conversions
    conv_x_kernel<<<4096, 256, 0, stream>>>(x, comb);
    conv_w_kernel<<<1536, 256, 0, stream>>>(Wv, Wvb, Wg, Wgb);

    // 2. v = x @ Wv^T + bv  (bf16 out); BM=64,BN=256 keeps 512 blocks for N=512
    gemm_bt<64, 256, false, true><<<dim3(BS_ / 64, M_ / 256), 256, 0, stream>>>(
        comb, E_, Wvb, D_, vbuf, M_, bv, nullptr, 0, D_);

    // 3. chunk-parallel scan -> wv bf16 into comb[:,2048:] + next_memory_state
    scan_p1<<<(B_ * CH_ * M_) / 256, 256, 0, stream>>>(vbuf, tdec, Ebuf);
    scan_p3<<<(B_ * CH_ * M_) / 256, 256, 0, stream>>>(vbuf, tdec, tfir, ms, Ebuf, comb, out_state);

    // 4. out = x + combined @ Wg^T + bg  (256x256, 1-barrier/tile, XCD row-slabs)
    gemm_bt8<true, false, BS_ / 256><<<(BS_ / 256) * (D_ / 256), 512, 0, stream>>>(
        comb, E_, Wgb, E_, out, D_, bg, comb, E_, E_);
}

// Round 8
// 494.901 us; speedup vs baseline: 1.0664x; 1.0664x over previous
//
#include <hip/hip_runtime.h>
#include <hip/hip_bf16.h>
#include <stdint.h>

#define B_ 4
#define S_ 4096
#define D_ 2048
#define M_ 512
#define E_ (D_ + M_)   // 2560 combined width
#define BS_ (B_ * S_)  // 16384 rows
#define CH_ 32         // scan chunks per sequence
#define CL_ 128        // chunk length (CH_*CL_ == S_)

typedef __attribute__((ext_vector_type(8))) short short8;
typedef __attribute__((ext_vector_type(4))) short short4e;
typedef __attribute__((ext_vector_type(4))) float float4e;

__device__ __forceinline__ unsigned short f2bf(float f) {
    unsigned int u = __float_as_uint(f);
    u = (u + 0x7fffu + ((u >> 16) & 1u)) >> 16;   // RNE
    return (unsigned short)u;
}
__device__ __forceinline__ float bf2f(unsigned short h) {
    return __uint_as_float(((unsigned int)h) << 16);
}
__device__ __forceinline__ float sigmoidf(float x) {
    return 1.0f / (1.0f + expf(-x));
}

// ---- async global -> LDS, 16B per lane -------------------------------------
__device__ __forceinline__ void load_lds16(const unsigned short* g, unsigned short* l) {
    __builtin_amdgcn_global_load_lds(
        (const __attribute__((address_space(1))) unsigned int*)g,
        (__attribute__((address_space(3))) unsigned int*)l,
        16, 0, 0);
}

// ---- fp32 -> bf16 conversion: x into comb[:, 0:2048] (row stride E_) -------
__global__ void conv_x_kernel(const float* __restrict__ x, unsigned short* __restrict__ comb) {
    int i = blockIdx.x * blockDim.x + threadIdx.x;
    const int n4 = BS_ * D_ / 4;
    const int stride = gridDim.x * blockDim.x;
    for (; i < n4; i += stride) {
        int flat = i << 2;
        int row = flat >> 11;              // D_ = 2048
        int col = flat & (D_ - 1);
        float4 xv = ((const float4*)x)[i];
        short4e o = { (short)f2bf(xv.x), (short)f2bf(xv.y),
                      (short)f2bf(xv.z), (short)f2bf(xv.w) };
        *(short4e*)(comb + (size_t)row * E_ + col) = o;
    }
}

// ---- fp32 -> bf16 for both weight matrices in one launch -------------------
__global__ void conv_w_kernel(const float* __restrict__ Wv, unsigned short* __restrict__ Wvb,
                              const float* __restrict__ Wg, unsigned short* __restrict__ Wgb) {
    const int nv4 = M_ * D_ / 4;
    const int ng4 = D_ * E_ / 4;
    int i = blockIdx.x * blockDim.x + threadIdx.x;
    const int stride = gridDim.x * blockDim.x;
    for (; i < nv4 + ng4; i += stride) {
        const float* in;
        unsigned short* out;
        int j;
        if (i < nv4) { in = Wv; out = Wvb; j = i; }
        else         { in = Wg; out = Wgb; j = i - nv4; }
        float4 xv = ((const float4*)in)[j];
        short4e o = { (short)f2bf(xv.x), (short)f2bf(xv.y),
                      (short)f2bf(xv.z), (short)f2bf(xv.w) };
        ((short4e*)out)[j] = o;
    }
}

// ---- bf16 GEMM, B^T layout: C[m,n] = sum_k A[m,k]*B[n,k] (+bias, +resid) ---
// 2-barrier K-loop structure, kept for GEMM1 (N=512 -> needs small-N tiling)
template<int BM, int BN, bool ADDX, bool OUT_BF16>
__global__ __launch_bounds__(256) void gemm_bt(
    const unsigned short* __restrict__ A, int lda,
    const unsigned short* __restrict__ Bm, int ldb,
    void* __restrict__ Cv, int ldc,
    const float* __restrict__ bias,
    const unsigned short* __restrict__ resid, int resid_ld,
    int K)
{
    constexpr int MI = BM / 32;
    constexpr int NJ = BN / 32;
    constexpr int NGA = BM / 32;
    constexpr int NGB = BN / 32;

    __shared__ unsigned short As[BM * 64];
    __shared__ unsigned short Bs[BN * 64];

    const int tid  = threadIdx.x;
    const int lane = tid & 63;
    const int wave = __builtin_amdgcn_readfirstlane(tid >> 6);
    const int bm0  = blockIdx.x * BM;
    const int bn0  = blockIdx.y * BN;
    const int wm   = wave & 1;
    const int wn   = wave >> 1;
    const int lm   = lane & 15;
    const int quad = lane >> 4;

    const unsigned short* ag[NGA];
    unsigned short* al[NGA];
#pragma unroll
    for (int i = 0; i < NGA; ++i) {
        int g = i * 256 + tid;
        int r = g >> 3, c = g & 7;
        int cg = c ^ (r & 7);
        ag[i] = A + (size_t)(bm0 + r) * lda + cg * 8;
        al[i] = As + (i * 256 + wave * 64) * 8;
    }
    const unsigned short* bgp[NGB];
    unsigned short* bl[NGB];
#pragma unroll
    for (int i = 0; i < NGB; ++i) {
        int g = i * 256 + tid;
        int r = g >> 3, c = g & 7;
        int cg = c ^ (r & 7);
        bgp[i] = Bm + (size_t)(bn0 + r) * ldb + cg * 8;
        bl[i] = Bs + (i * 256 + wave * 64) * 8;
    }

    float4e acc[MI][NJ];
    const float4e zero = {0.f, 0.f, 0.f, 0.f};
#pragma unroll
    for (int i = 0; i < MI; ++i)
#pragma unroll
        for (int j = 0; j < NJ; ++j) acc[i][j] = zero;

    for (int k0 = 0; k0 < K; k0 += 64) {
#pragma unroll
        for (int i = 0; i < NGA; ++i) load_lds16(ag[i] + k0, al[i]);
#pragma unroll
        for (int i = 0; i < NGB; ++i) load_lds16(bgp[i] + k0, bl[i]);
        __syncthreads();
#pragma unroll
        for (int kk = 0; kk < 2; ++kk) {
            short8 af[MI], bf[NJ];
#pragma unroll
            for (int i = 0; i < MI; ++i) {
                int ra = wm * (BM / 2) + i * 16 + lm;
                af[i] = *(const short8*)(As + ra * 64 + (((kk * 4 + quad) ^ (ra & 7)) * 8));
            }
#pragma unroll
            for (int j = 0; j < NJ; ++j) {
                int rb = wn * (BN / 2) + j * 16 + lm;
                bf[j] = *(const short8*)(Bs + rb * 64 + (((kk * 4 + quad) ^ (rb & 7)) * 8));
            }
#pragma unroll
            for (int i = 0; i < MI; ++i)
#pragma unroll
                for (int j = 0; j < NJ; ++j)
                    acc[i][j] = __builtin_amdgcn_mfma_f32_16x16x32_bf16(af[i], bf[j], acc[i][j], 0, 0, 0);
        }
        __syncthreads();
    }

#pragma unroll
    for (int i = 0; i < MI; ++i) {
#pragma unroll
        for (int j = 0; j < NJ; ++j) {
            int row = bm0 + wm * (BM / 2) + i * 16 + quad * 4;
            int col = bn0 + wn * (BN / 2) + j * 16 + lm;
            float bb = bias[col];
#pragma unroll
            for (int r = 0; r < 4; ++r) {
                size_t idx = (size_t)(row + r) * ldc + col;
                float val = acc[i][j][r] + bb;
                if (ADDX) val += bf2f(resid[(size_t)(row + r) * resid_ld + col]);
                if (OUT_BF16) ((unsigned short*)Cv)[idx] = f2bf(val);
                else          ((float*)Cv)[idx] = val;
            }
        }
    }
}

// ---- 256x256 GEMM, faithful m201 8-phase schedule ---------------------------
// r7: r5/r6 (coarse staging, vmcnt once/tile) both pinned at ~218us — exactly
// m196's documented failure mode ("coarse phase-split without the fine
// ds_read || G::load || MFMA interleave HURTS"). This version is the m201
// template: BK=64, LDS [2 dbuf][2 K-halves] x (256 rows x 32 cols) per
// operand (128 KiB), 4 phases per K-tile. Each phase:
//   {ds_read cluster || stage ONE half-tile (2 gload_lds)} -> s_barrier ->
//   lgkmcnt(0)+schedbar -> setprio(1) -> 16 MFMA -> setprio(0) -> s_barrier
// Stage order per tile t (into dbuf nxt, for tile t+1): A-k0, B-k0, A-k1, B-k1
// (consumption order). vmcnt(4) ONLY at ends of phases 1 and 3: outstanding
// oscillates 4..8, never drains. Ledger: at t+1 P0 the oldest 4 (A0',B0')
// must be retired -> vmcnt(4) at t P3-end; at t+1 P2 the next 4 (A1',B1')
// -> vmcnt(4) at t+1 P1-end. WAR: slot staged at t Pp was last read at
// t-1 Pp (lgkm-retired, 2+ barriers earlier). Prologue: 8 loads (tile 0),
// vmcnt(4), barrier.
template<bool ADDX, bool OUT_BF16, int MT>
__global__ __launch_bounds__(512, 2) void gemm_bt8(
    const unsigned short* __restrict__ A, int lda,
    const unsigned short* __restrict__ Bm, int ldb,
    void* __restrict__ Cv, int ldc,
    const float* __restrict__ bias,
    const unsigned short* __restrict__ resid, int resid_ld,
    int K)
{
    __shared__ unsigned short As[2][2][256 * 32];   // [dbuf][k-half], 64 KB
    __shared__ unsigned short Bs[2][2][256 * 32];   // 64 KB

    const int tid  = threadIdx.x;
    const int lane = tid & 63;
    const int wave = __builtin_amdgcn_readfirstlane(tid >> 6);
    const int wm   = wave >> 2;      // 0..1  (M half)
    const int wn   = wave & 3;       // 0..3  (N quarter)
    const int lm   = lane & 15;
    const int quad = lane >> 4;

    // XCD mapping: xcd = bid&7 owns row-tiles [xcd*RPX,(xcd+1)*RPX), cols slow.
    constexpr int RPX = MT / 8;
    const int bid = blockIdx.x;
    const int xcd = bid & 7;
    const int w   = bid >> 3;
    const int row = xcd * RPX + (w % RPX);
    const int col = w / RPX;
    const int bm0 = row * 256;
    const int bn0 = col * 256;

    // staging thread->granule map (per half-tile: 256 rows x 4 granules of 16B)
    // LDS granule (r,c) holds global granule (r, c^((r>>1)&3)) — proven
    // conflict-free with the matching read swizzle (r5/r6: SQ_LDS_BANK_CONFLICT=0)
    const unsigned short* aG[2];
    const unsigned short* bG[2];
    int ldsOff[2];
#pragma unroll
    for (int l = 0; l < 2; ++l) {
        int g = l * 512 + tid;
        int r = g >> 2, c = g & 3;
        int cg = c ^ ((r >> 1) & 3);
        aG[l] = A  + (size_t)(bm0 + r) * lda + cg * 8;
        bG[l] = Bm + (size_t)(bn0 + r) * ldb + cg * 8;
        ldsOff[l] = (l * 512 + wave * 64) * 8;   // wave-uniform base (shorts)
    }

    float4e acc[8][4];
    const float4e zero = {0.f, 0.f, 0.f, 0.f};
#pragma unroll
    for (int i = 0; i < 8; ++i)
#pragma unroll
        for (int j = 0; j < 4; ++j) acc[i][j] = zero;

    const int NT = K >> 6;           // K-tiles of 64 (E_=2560 -> 40)

    // prologue: stage tile 0 (A-k0, B-k0, A-k1, B-k1 = 8 loads), wait oldest 4
#pragma unroll
    for (int l = 0; l < 2; ++l) load_lds16(aG[l],      &As[0][0][ldsOff[l]]);
#pragma unroll
    for (int l = 0; l < 2; ++l) load_lds16(bG[l],      &Bs[0][0][ldsOff[l]]);
#pragma unroll
    for (int l = 0; l < 2; ++l) load_lds16(aG[l] + 32, &As[0][1][ldsOff[l]]);
#pragma unroll
    for (int l = 0; l < 2; ++l) load_lds16(bG[l] + 32, &Bs[0][1][ldsOff[l]]);
    asm volatile("s_waitcnt vmcnt(4)");
    __builtin_amdgcn_sched_barrier(0);
    __builtin_amdgcn_s_barrier();
    __builtin_amdgcn_sched_barrier(0);

    // fragment ds_read offsets (shorts, within a 256x32 half): row*32 + swz*8
    const int swz8 = (quad ^ ((lm >> 1) & 3)) << 3;
    const int aoff = (wm * 128 + lm) * 32 + swz8;
    const int boff = (wn * 64  + lm) * 32 + swz8;

    int cur = 0;
    for (int t = 0; t < NT; ++t) {
        const int nxt = cur ^ 1;
        int tp = t + 1; if (tp > NT - 1) tp = NT - 1;   // tail: dummy re-stage
        const int kp = tp << 6;                          // K-offset (shorts)
        const unsigned short* A0 = &As[cur][0][0];
        const unsigned short* A1 = &As[cur][1][0];
        const unsigned short* B0 = &Bs[cur][0][0];
        const unsigned short* B1 = &Bs[cur][1][0];

        short8 af[8], bf0, bf1, bf2, bf3;

        // ---- P0: af(k0) x8 + bf01(k0); stage A-k0(t+1); MFMA j=0,1 ----------
#pragma unroll
        for (int i = 0; i < 8; ++i) af[i] = *(const short8*)(A0 + aoff + i * 512);
        bf0 = *(const short8*)(B0 + boff);
        bf1 = *(const short8*)(B0 + boff + 512);
#pragma unroll
        for (int l = 0; l < 2; ++l) load_lds16(aG[l] + kp, &As[nxt][0][ldsOff[l]]);
        __builtin_amdgcn_s_barrier();
        asm volatile("s_waitcnt lgkmcnt(0)");
        __builtin_amdgcn_sched_barrier(0);
        __builtin_amdgcn_s_setprio(1);
#pragma unroll
        for (int i = 0; i < 8; ++i) {
            acc[i][0] = __builtin_amdgcn_mfma_f32_16x16x32_bf16(af[i], bf0, acc[i][0], 0, 0, 0);
            acc[i][1] = __builtin_amdgcn_mfma_f32_16x16x32_bf16(af[i], bf1, acc[i][1], 0, 0, 0);
        }
        __builtin_amdgcn_s_setprio(0);
        __builtin_amdgcn_s_barrier();

        // ---- P1: bf23(k0); stage B-k0(t+1); MFMA j=2,3; vmcnt(4) ------------
        bf2 = *(const short8*)(B0 + boff + 1024);
        bf3 = *(const short8*)(B0 + boff + 1536);
#pragma unroll
        for (int l = 0; l < 2; ++l) load_lds16(bG[l] + kp, &Bs[nxt][0][ldsOff[l]]);
        __builtin_amdgcn_s_barrier();
        asm volatile("s_waitcnt lgkmcnt(0)");
        __builtin_amdgcn_sched_barrier(0);
        __builtin_amdgcn_s_setprio(1);
#pragma unroll
        for (int i = 0; i < 8; ++i) {
            acc[i][2] = __builtin_amdgcn_mfma_f32_16x16x32_bf16(af[i], bf2, acc[i][2], 0, 0, 0);
            acc[i][3] = __builtin_amdgcn_mfma_f32_16x16x32_bf16(af[i], bf3, acc[i][3], 0, 0, 0);
        }
        __builtin_amdgcn_s_setprio(0);
        asm volatile("s_waitcnt vmcnt(4)");
        __builtin_amdgcn_sched_barrier(0);
        __builtin_amdgcn_s_barrier();

        // ---- P2: af(k1) x8 + bf01(k1); stage A-k1(t+1); MFMA j=0,1 ----------
#pragma unroll
        for (int i = 0; i < 8; ++i) af[i] = *(const short8*)(A1 + aoff + i * 512);
        bf0 = *(const short8*)(B1 + boff);
        bf1 = *(const short8*)(B1 + boff + 512);
#pragma unroll
        for (int l = 0; l < 2; ++l) load_lds16(aG[l] + kp + 32, &As[nxt][1][ldsOff[l]]);
        __builtin_amdgcn_s_barrier();
        asm volatile("s_waitcnt lgkmcnt(0)");
        __builtin_amdgcn_sched_barrier(0);
        __builtin_amdgcn_s_setprio(1);
#pragma unroll
        for (int i = 0; i < 8; ++i) {
            acc[i][0] = __builtin_amdgcn_mfma_f32_16x16x32_bf16(af[i], bf0, acc[i][0], 0, 0, 0);
            acc[i][1] = __builtin_amdgcn_mfma_f32_16x16x32_bf16(af[i], bf1, acc[i][1], 0, 0, 0);
        }
        __builtin_amdgcn_s_setprio(0);
        __builtin_amdgcn_s_barrier();

        // ---- P3: bf23(k1); stage B-k1(t+1); MFMA j=2,3; vmcnt(4) ------------
        bf2 = *(const short8*)(B1 + boff + 1024);
        bf3 = *(const short8*)(B1 + boff + 1536);
#pragma unroll
        for (int l = 0; l < 2; ++l) load_lds16(bG[l] + kp + 32, &Bs[nxt][1][ldsOff[l]]);
        __builtin_amdgcn_s_barrier();
        asm volatile("s_waitcnt lgkmcnt(0)");
        __builtin_amdgcn_sched_barrier(0);
        __builtin_amdgcn_s_setprio(1);
#pragma unroll
        for (int i = 0; i < 8; ++i) {
            acc[i][2] = __builtin_amdgcn_mfma_f32_16x16x32_bf16(af[i], bf2, acc[i][2], 0, 0, 0);
            acc[i][3] = __builtin_amdgcn_mfma_f32_16x16x32_bf16(af[i], bf3, acc[i][3], 0, 0, 0);
        }
        __builtin_amdgcn_s_setprio(0);
        asm volatile("s_waitcnt vmcnt(4)");
        __builtin_amdgcn_sched_barrier(0);
        __builtin_amdgcn_s_barrier();

        cur = nxt;
    }

    // epilogue: C/D layout col = lane&15, row = quad*4 + reg
#pragma unroll
    for (int i = 0; i < 8; ++i) {
#pragma unroll
        for (int j = 0; j < 4; ++j) {
            int crow = bm0 + wm * 128 + i * 16 + quad * 4;
            int ccol = bn0 + wn * 64  + j * 16 + lm;
            float bb = bias[ccol];
#pragma unroll
            for (int r = 0; r < 4; ++r) {
                size_t idx = (size_t)(crow + r) * ldc + ccol;
                float val = acc[i][j][r] + bb;
                if (ADDX) val += bf2f(resid[(size_t)(crow + r) * resid_ld + ccol]);
                if (OUT_BF16) ((unsigned short*)Cv)[idx] = f2bf(val);
                else          ((float*)Cv)[idx] = val;
            }
        }
    }
}

// ---- scan pass 1: per-chunk local end state (init 0), bf16 v ---------------
__global__ void scan_p1(const unsigned short* __restrict__ v, const float* __restrict__ tdp,
                        float* __restrict__ Ebuf) {
    int tid = blockIdx.x * blockDim.x + threadIdx.x;
    int m = tid & (M_ - 1);
    int c = (tid >> 9) & (CH_ - 1);
    int b = tid >> 14;
    float td = 0.9f * sigmoidf(tdp[m]) + 0.1f;
    const unsigned short* vp = v + (size_t)(b * S_ + c * CL_) * M_ + m;
    float s = 0.f;
#pragma unroll 4
    for (int t = 0; t < CL_; ++t) s = td * s + bf2f(vp[(size_t)t * M_]);
    Ebuf[(b * CH_ + c) * M_ + m] = s;
}

// ---- scan pass 2 (prefix inlined) + emit wv bf16 + final state -------------
__global__ void scan_p3(const unsigned short* __restrict__ v, const float* __restrict__ tdp,
                        const float* __restrict__ tfp, const float* __restrict__ ms,
                        const float* __restrict__ Ebuf, unsigned short* __restrict__ comb,
                        float* __restrict__ out_state) {
    int tid = blockIdx.x * blockDim.x + threadIdx.x;
    int m = tid & (M_ - 1);
    int c = (tid >> 9) & (CH_ - 1);
    int b = tid >> 14;
    float td  = 0.9f * sigmoidf(tdp[m]) + 0.1f;
    float a = td;
#pragma unroll
    for (int i = 0; i < 7; ++i) a *= a;                // td^128
    float s = 0.f;
    for (int cp = 0; cp < c; ++cp)
        s = a * s + Ebuf[(b * CH_ + cp) * M_ + m];
    float add = ms[b * M_ + m] * sigmoidf(tfp[m]);
    const unsigned short* vp = v + (size_t)(b * S_ + c * CL_) * M_ + m;
    unsigned short* cp_ = comb + (size_t)(b * S_ + c * CL_) * E_ + D_ + m;
    float w = 0.f;
#pragma unroll 4
    for (int t = 0; t < CL_; ++t) {
        s = td * s + bf2f(vp[(size_t)t * M_]);
        w = s + add;
        cp_[(size_t)t * E_] = f2bf(w);
    }
    if (c == CH_ - 1) out_state[b * M_ + m] = w;
}

extern "C" void kernel_launch(void* const* d_in, const int* in_sizes, int n_in,
                              void* d_out, int out_size, void* d_ws, size_t ws_size,
                              hipStream_t stream) {
    const float* x    = (const float*)d_in[0];
    const float* ms   = (const float*)d_in[1];
    // d_in[2]=Wk, d_in[3]=bk are dead code in the reference
    const float* Wv   = (const float*)d_in[4];
    const float* bv   = (const float*)d_in[5];
    const float* Wg   = (const float*)d_in[6];
    const float* bg   = (const float*)d_in[7];
    const float* tdec = (const float*)d_in[8];
    const float* tfir = (const float*)d_in[9];

    float* out       = (float*)d_out;
    float* out_state = out + (size_t)BS_ * D_;

    char* ws = (char*)d_ws;
    size_t off = 0;
    unsigned short* comb = (unsigned short*)(ws + off); off += (size_t)BS_ * E_ * 2;  // 84 MB
    unsigned short* vbuf = (unsigned short*)(ws + off); off += (size_t)BS_ * M_ * 2;  // 16.8 MB
    unsigned short* Wvb  = (unsigned short*)(ws + off); off += (size_t)M_ * D_ * 2;   // 2 MB
    unsigned short* Wgb  = (unsigned short*)(ws + off); off += (size_t)D_ * E_ * 2;   // 10.5 MB
    float*          Ebuf = (float*)(ws + off);          off += (size_t)B_ * CH_ * M_ * 4;

    // 1. conversions
    conv_x_kernel<<<4096, 256, 0, stream>>>(x, comb);
    conv_w_kernel<<<1536, 256, 0, stream>>>(Wv, Wvb, Wg, Wgb);

    // 2. v = x @ Wv^T + bv  (bf16 out); BM=64,BN=256 keeps 512 blocks for N=512
    gemm_bt<64, 256, false, true><<<dim3(BS_ / 64, M_ / 256), 256, 0, stream>>>(
        comb, E_, Wvb, D_, vbuf, M_, bv, nullptr, 0, D_);

    // 3. chunk-parallel scan -> wv bf16 into comb[:,2048:] + next_memory_state
    scan_p1<<<(B_ * CH_ * M_) / 256, 256, 0, stream>>>(vbuf, tdec, Ebuf);
    scan_p3<<<(B_ * CH_ * M_) / 256, 256, 0, stream>>>(vbuf, tdec, tfir, ms, Ebuf, comb, out_state);

    // 4. out = x + combined @ Wg^T + bg  (256x256 m201 8-phase, XCD row-slabs)
    gemm_bt8<true, false, BS_ / 256><<<(BS_ / 256) * (D_ / 256), 512, 0, stream>>>(
        comb, E_, Wgb, E_, out, D_, bg, comb, E_, E_);
}